// Round 1
// baseline (818.129 us; speedup 1.0000x reference)
//
#include <hip/hip_runtime.h>

// LIF forward scan:
//   u = 0.5*u + x[t]; s = (u >= 1); u -= s; out[t] = s
// T=16 sequential steps per independent spatial position.
// N_POS = BATCH*C*H*W = 32*64*32*32 = 2,097,152 independent sequences.
// Layout: x[t*N_POS + i]. One thread owns 4 consecutive i (float4),
// loops over t with u carried in registers. Fully coalesced, 16 B/lane.

#define T_STEPS 16
#define N_POS   (32 * 64 * 32 * 32)       // 2,097,152
#define N4      (N_POS / 4)               // 524,288 float4 groups per t

__global__ __launch_bounds__(256) void lif_scan_kernel(
    const float4* __restrict__ x, float4* __restrict__ out)
{
    const int gid = blockIdx.x * blockDim.x + threadIdx.x;  // 0 .. N4-1
    float4 u = make_float4(0.f, 0.f, 0.f, 0.f);

    #pragma unroll
    for (int t = 0; t < T_STEPS; ++t) {
        const size_t idx = (size_t)t * (size_t)N4 + (size_t)gid;
        float4 xt = x[idx];
        float4 s;
        u.x = 0.5f * u.x + xt.x; s.x = (u.x >= 1.0f) ? 1.0f : 0.0f; u.x -= s.x;
        u.y = 0.5f * u.y + xt.y; s.y = (u.y >= 1.0f) ? 1.0f : 0.0f; u.y -= s.y;
        u.z = 0.5f * u.z + xt.z; s.z = (u.z >= 1.0f) ? 1.0f : 0.0f; u.z -= s.z;
        u.w = 0.5f * u.w + xt.w; s.w = (u.w >= 1.0f) ? 1.0f : 0.0f; u.w -= s.w;
        out[idx] = s;
    }
}

extern "C" void kernel_launch(void* const* d_in, const int* in_sizes, int n_in,
                              void* d_out, int out_size, void* d_ws, size_t ws_size,
                              hipStream_t stream)
{
    const float4* x  = (const float4*)d_in[0];   // inputs [T*B, 64, 32, 32] f32
    float4* out      = (float4*)d_out;           // spikes, same shape, f32
    // d_in[1] (random_tangents) is unused by the reference output.

    const int threads = 256;
    const int blocks  = N4 / threads;            // 524288 / 256 = 2048
    lif_scan_kernel<<<blocks, threads, 0, stream>>>(x, out);
}